// Round 14
// baseline (95.521 us; speedup 1.0000x reference)
//
#include <hip/hip_runtime.h>
#include <hip/hip_bf16.h>

#define CIN 128
#define COUT 256
#define H 56
#define W 56
#define OH 54
#define OW 54

typedef __attribute__((ext_vector_type(8))) short short8;
typedef __attribute__((ext_vector_type(4))) float floatx4;

typedef __attribute__((address_space(3))) unsigned int  lds_u32;
typedef const __attribute__((address_space(1))) unsigned int glb_u32;

static __device__ __forceinline__ unsigned short f2bf(float f) {
  unsigned int u = __builtin_bit_cast(unsigned int, f);
  u += 0x7fffu + ((u >> 16) & 1u);   // RNE
  return (unsigned short)(u >> 16);
}

// ---------- prepass 1: w[co][ci][kh][kw] f32 -> w2[k16][co][8] bf16 ----------
// k16 = (kh*3+kw)*16 + c8 ; ci = c8*8 + j
__global__ void repack_w(const float* __restrict__ w, unsigned short* __restrict__ w2) {
  int idx = blockIdx.x * 256 + threadIdx.x;
  if (idx >= COUT * CIN * 9) return;
  int kw = idx % 3, t1 = idx / 3;
  int kh = t1 % 3, t2 = t1 / 3;
  int ci = t2 % CIN;
  int co = t2 / CIN;
  int c8 = ci >> 3, j = ci & 7;
  w2[((((kh * 3 + kw) * 16 + c8) * COUT + co) * 8) + j] = f2bf(w[idx]);
}

// ---------- prepass 2 (LDS transpose, coalesced both sides) ----------
// x NCHW f32 -> xb[n][h][g'] bf16, g' = iw*16 + (c16 ^ (iw&7)).
__global__ __launch_bounds__(256) void repack_x(const float* __restrict__ x,
                                                unsigned short* __restrict__ xb) {
  __shared__ float xt[56][129];
  const int h = blockIdx.x;       // 0..55
  const int n = blockIdx.y;       // 0..31
  const float* src = x + (size_t)n * CIN * (H * W) + h * W;
  #pragma unroll
  for (int r = 0; r < 28; ++r) {
    int idx = r * 256 + threadIdx.x;
    int ci = idx / 56, iw = idx % 56;
    xt[iw][ci] = src[ci * (H * W) + iw];
  }
  __syncthreads();
  unsigned short* dst = xb + ((size_t)n * H + h) * 896 * 8;
  #pragma unroll
  for (int r = 0; r < 4; ++r) {
    int g = r * 256 + threadIdx.x;
    if (g < 896) {
      int iw = g >> 4, c16 = g & 15;
      short8 v;
      #pragma unroll
      for (int j = 0; j < 8; ++j)
        v[j] = (short)f2bf(xt[iw][c16 * 8 + j]);
      int gp = iw * 16 + (c16 ^ (iw & 7));
      *reinterpret_cast<short8*>(&dst[gp * 8]) = v;
    }
  }
}

// ---------- main conv: FAT waves (m=8) ----------
// 256 threads = 4 waves = 2 co-halves x 2 rows; wave = 128 co x 64 px.
// Per k-step: 8 A-loads + 4 B-reads feed 32 MFMA (155 cyc) -> the ~320 cyc
// un-hidden A-wait measured in r13 is amortized over 2x the MFMA issue.
// acc[8][4]=128 regs; NO explicit pipeline (r5's spill came from acc+pipeline).
__global__ __launch_bounds__(256, 2) void conv7(
    const unsigned short* __restrict__ xb, const unsigned short* __restrict__ w2,
    const float* __restrict__ bias, float* __restrict__ out) {
  __shared__ alignas(16) unsigned short xs[3744 * 8];   // 4 rows + overrun pad = 59,904 B

  // XCD-bijective swizzle: 864 % 8 == 0
  const int f = blockIdx.x;
  const int swz = (f & 7) * 108 + (f >> 3);
  const int ohp = swz % 27;
  const int n   = swz / 27;
  const int oh0 = ohp * 2;
  const int tid = threadIdx.x;
  const int wid  = tid >> 6;
  const int lane = tid & 63;

  // ---- stage rows oh0..oh0+3 (3584 granules) via global_load_lds, 14/wave ----
  {
    const unsigned short* src = xb + ((size_t)n * H + oh0) * 896 * 8;
    #pragma unroll
    for (int i = 0; i < 14; ++i) {
      int idx = (wid * 14 + i) * 64;
      __builtin_amdgcn_global_load_lds(
          (glb_u32*)(src + (size_t)(idx + lane) * 8),
          (lds_u32*)(&xs[idx * 8]), 16, 0, 0);
    }
  }
  asm volatile("s_waitcnt vmcnt(0)" ::: "memory");
  __syncthreads();

  const int wm   = wid >> 1;       // co half (0/1) -> 128 couts
  const int wn   = wid & 1;        // output row within the pair
  const int l16  = lane & 15;
  const int cig  = lane >> 4;      // 0..3
  const int co_base = wm * 128;
  const int oh = oh0 + wn;
  const int rowd = cig * 4;

  floatx4 acc[8][4];
  #pragma unroll
  for (int m = 0; m < 8; ++m)
    #pragma unroll
    for (int nr = 0; nr < 4; ++nr)
      acc[m][nr] = (floatx4){0.f, 0.f, 0.f, 0.f};

  #pragma unroll
  for (int s = 0; s < 36; ++s) {
    const int kh = s / 12, ch = (s / 3) & 3, kw = s % 3;
    const int row = wn + kh;       // 0..3
    // A fragments: direct from global (L2/L1-resident repacked weights);
    // the row-twin wave reads the same 8 KB -> L1 hit.
    const unsigned short* wp =
        w2 + ((size_t)(((kh * 3 + kw) * 16 + (ch * 4 + cig)) * COUT + co_base + l16)) * 8;
    short8 a[8];
    #pragma unroll
    for (int m = 0; m < 8; ++m)
      a[m] = *reinterpret_cast<const short8*>(wp + m * 128);
    // B fragments: swizzled LDS reads
    const int iwl = l16 + kw;
    const int c16x = (ch * 4 + cig) ^ (iwl & 7);
    const int boff = (row * 896 + iwl * 16 + c16x) * 8;
    short8 b[4];
    #pragma unroll
    for (int nr = 0; nr < 4; ++nr)
      b[nr] = *reinterpret_cast<const short8*>(&xs[boff + nr * 2048]);

    __builtin_amdgcn_s_setprio(1);
    #pragma unroll
    for (int m = 0; m < 8; ++m)
      #pragma unroll
      for (int nr = 0; nr < 4; ++nr)
        acc[m][nr] = __builtin_amdgcn_mfma_f32_16x16x32_bf16(a[m], b[nr], acc[m][nr], 0, 0, 0);
    __builtin_amdgcn_s_setprio(0);
  }

  // ---- epilogue: C/D layout col=lane&15, row=(lane>>4)*4+reg; bias loaded here ----
  #pragma unroll
  for (int m = 0; m < 8; ++m) {
    #pragma unroll
    for (int reg = 0; reg < 4; ++reg) {
      int co = co_base + m * 16 + rowd + reg;
      float bvv = bias[co];
      float* op = out + (((size_t)n * COUT + co) * OH + oh) * OW;
      #pragma unroll
      for (int nr = 0; nr < 4; ++nr) {
        int ow = nr * 16 + l16;
        if (ow < OW) op[ow] = acc[m][nr][reg] + bvv;
      }
    }
  }
}

// ================== fallback path (ws too small): round-2 kernel ==================
#define CSTR 136
#define IWP 66

__global__ __launch_bounds__(512, 4) void conv_fb(
    const float* __restrict__ x, const unsigned short* __restrict__ w2,
    const float* __restrict__ bias, float* __restrict__ out) {
  __shared__ alignas(16) unsigned short xsf[4 * IWP * CSTR];

  const int ohp = blockIdx.x;
  const int n   = blockIdx.y;
  const int oh0 = ohp * 2;
  const int tid = threadIdx.x;

  {
    short8 zz = {0, 0, 0, 0, 0, 0, 0, 0};
    for (int i = tid; i < 4 * 10 * 17; i += 512) {
      int r = i / 170, rem = i % 170;
      int iw = 56 + rem / 17, g = rem % 17;
      *reinterpret_cast<short8*>(&xsf[(r * IWP + iw) * CSTR + g * 8]) = zz;
    }
  }
  for (int s = tid; s < 3584; s += 512) {
    int iw = s % 56;
    int t  = s / 56;
    int c8 = t & 15, r = t >> 4;
    const float* xp = x + (size_t)n * CIN * (H * W) + (oh0 + r) * W + iw;
    short8 v;
    #pragma unroll
    for (int j = 0; j < 8; ++j)
      v[j] = (short)f2bf(xp[(size_t)(c8 * 8 + j) * (H * W)]);
    *reinterpret_cast<short8*>(&xsf[(r * IWP + iw) * CSTR + c8 * 8]) = v;
  }
  __syncthreads();

  const int wid  = tid >> 6;
  const int lane = tid & 63;
  const int wm   = wid >> 1;
  const int wn   = wid & 1;
  const int l16  = lane & 15;
  const int cig  = lane >> 4;

  const int co_base = wm * 64;
  const int oh = oh0 + wn;

  floatx4 acc[4][4];
  #pragma unroll
  for (int m = 0; m < 4; ++m)
    #pragma unroll
    for (int nr = 0; nr < 4; ++nr)
      acc[m][nr] = (floatx4){0.f, 0.f, 0.f, 0.f};

  for (int kh = 0; kh < 3; ++kh) {
    const int row = wn + kh;
    #pragma unroll
    for (int ch = 0; ch < 4; ++ch) {
      const int bbase = (row * IWP + l16) * CSTR + ch * 32 + cig * 8;
      #pragma unroll
      for (int kw = 0; kw < 3; ++kw) {
        const unsigned short* wp =
            w2 + ((size_t)(((kh * 3 + kw) * 16 + (ch * 4 + cig)) * COUT + co_base + l16)) * 8;
        short8 a[4];
        #pragma unroll
        for (int m = 0; m < 4; ++m)
          a[m] = *reinterpret_cast<const short8*>(wp + m * 16 * 8);
        short8 b[4];
        #pragma unroll
        for (int nr = 0; nr < 4; ++nr)
          b[nr] = *reinterpret_cast<const short8*>(&xsf[bbase + (nr * 16 + kw) * CSTR]);
        #pragma unroll
        for (int m = 0; m < 4; ++m)
          #pragma unroll
          for (int nr = 0; nr < 4; ++nr)
            acc[m][nr] = __builtin_amdgcn_mfma_f32_16x16x32_bf16(a[m], b[nr], acc[m][nr], 0, 0, 0);
      }
    }
  }

  const int rowd = cig * 4;
  #pragma unroll
  for (int m = 0; m < 4; ++m) {
    #pragma unroll
    for (int reg = 0; reg < 4; ++reg) {
      int co = co_base + m * 16 + rowd + reg;
      float bvv = bias[co];
      float* op = out + (((size_t)n * COUT + co) * OH + oh) * OW;
      #pragma unroll
      for (int nr = 0; nr < 4; ++nr) {
        int ow = nr * 16 + l16;
        if (ow < OW) op[ow] = acc[m][nr][reg] + bvv;
      }
    }
  }
}

extern "C" void kernel_launch(void* const* d_in, const int* in_sizes, int n_in,
                              void* d_out, int out_size, void* d_ws, size_t ws_size,
                              hipStream_t stream) {
  (void)in_sizes; (void)n_in; (void)out_size;
  const float* x    = (const float*)d_in[0];
  const float* w    = (const float*)d_in[1];
  const float* bias = (const float*)d_in[2];
  float* out = (float*)d_out;

  const size_t W2_BYTES = (size_t)9 * 16 * COUT * 8 * 2;            // 589,824
  const size_t XB_BYTES = (size_t)32 * H * 896 * 8 * 2;             // 25,690,112
  unsigned short* w2 = (unsigned short*)d_ws;

  repack_w<<<dim3((COUT * CIN * 9 + 255) / 256), dim3(256), 0, stream>>>(w, w2);

  if (ws_size >= W2_BYTES + XB_BYTES) {
    unsigned short* xb = (unsigned short*)((char*)d_ws + W2_BYTES);
    repack_x<<<dim3(56, 32), dim3(256), 0, stream>>>(x, xb);
    conv7<<<dim3(864), dim3(256), 0, stream>>>(xb, w2, bias, out);
  } else {
    conv_fb<<<dim3(27, 32), dim3(512), 0, stream>>>(x, w2, bias, out);
  }
}

// Round 15
// 84.975 us; speedup vs baseline: 1.1241x; 1.1241x over previous
//
#include <hip/hip_runtime.h>
#include <hip/hip_bf16.h>

#define CIN 128
#define COUT 256
#define H 56
#define W 56
#define OH 54
#define OW 54

typedef __attribute__((ext_vector_type(8))) short short8;
typedef __attribute__((ext_vector_type(4))) float floatx4;

typedef __attribute__((address_space(3))) unsigned int  lds_u32;
typedef const __attribute__((address_space(1))) unsigned int glb_u32;

static __device__ __forceinline__ unsigned short f2bf(float f) {
  unsigned int u = __builtin_bit_cast(unsigned int, f);
  u += 0x7fffu + ((u >> 16) & 1u);   // RNE
  return (unsigned short)(u >> 16);
}

// ---------- prepass 1: w[co][ci][kh][kw] f32 -> w2[k16][co][8] bf16 ----------
__global__ void repack_w(const float* __restrict__ w, unsigned short* __restrict__ w2) {
  int idx = blockIdx.x * 256 + threadIdx.x;
  if (idx >= COUT * CIN * 9) return;
  int kw = idx % 3, t1 = idx / 3;
  int kh = t1 % 3, t2 = t1 / 3;
  int ci = t2 % CIN;
  int co = t2 / CIN;
  int c8 = ci >> 3, j = ci & 7;
  w2[((((kh * 3 + kw) * 16 + c8) * COUT + co) * 8) + j] = f2bf(w[idx]);
}

// ---------- prepass 2 (LDS transpose, coalesced both sides) ----------
// x NCHW f32 -> xb[n][h][g'] bf16, g' = iw*16 + (c16 ^ (iw&7)).
__global__ __launch_bounds__(256) void repack_x(const float* __restrict__ x,
                                                unsigned short* __restrict__ xb) {
  __shared__ float xt[56][129];
  const int h = blockIdx.x;       // 0..55
  const int n = blockIdx.y;       // 0..31
  const float* src = x + (size_t)n * CIN * (H * W) + h * W;
  #pragma unroll
  for (int r = 0; r < 28; ++r) {
    int idx = r * 256 + threadIdx.x;
    int ci = idx / 56, iw = idx % 56;
    xt[iw][ci] = src[ci * (H * W) + iw];
  }
  __syncthreads();
  unsigned short* dst = xb + ((size_t)n * H + h) * 896 * 8;
  #pragma unroll
  for (int r = 0; r < 4; ++r) {
    int g = r * 256 + threadIdx.x;
    if (g < 896) {
      int iw = g >> 4, c16 = g & 15;
      short8 v;
      #pragma unroll
      for (int j = 0; j < 8; ++j)
        v[j] = (short)f2bf(xt[iw][c16 * 8 + j]);
      int gp = iw * 16 + (c16 ^ (iw & 7));
      *reinterpret_cast<short8*>(&dst[gp * 8]) = v;
    }
  }
}

// ---------- main conv: padding-trimmed 2-row waves ----------
// 256 threads = 4 waves = 4 co-groups; block = 2 output rows x 256 co.
// Wave N-tile = 108 real px of the row pair -> 7 frags of 16 (3.6% pad vs
// 15.6% before): total MFMA 3.98M -> 3.48M (-12.5%). Per-lane (row,ow)
// tables address the 4-row slab; pad lanes read slab pad, stores masked.
__global__ __launch_bounds__(256, 2) void conv8(
    const unsigned short* __restrict__ xb, const unsigned short* __restrict__ w2,
    const float* __restrict__ bias, float* __restrict__ out) {
  __shared__ alignas(16) unsigned short xs[3744 * 8];   // 4 rows + overrun pad = 59,904 B

  // XCD-bijective swizzle: 864 % 8 == 0
  const int f = blockIdx.x;
  const int swz = (f & 7) * 108 + (f >> 3);
  const int ohp = swz % 27;
  const int n   = swz / 27;
  const int oh0 = ohp * 2;
  const int tid = threadIdx.x;
  const int wid  = tid >> 6;       // co group (0..3)
  const int lane = tid & 63;

  // ---- stage rows oh0..oh0+3 (3584 granules), 14 issues/wave ----
  {
    const unsigned short* src = xb + ((size_t)n * H + oh0) * 896 * 8;
    #pragma unroll
    for (int i = 0; i < 14; ++i) {
      int idx = (wid * 14 + i) * 64;
      __builtin_amdgcn_global_load_lds(
          (glb_u32*)(src + (size_t)(idx + lane) * 8),
          (lds_u32*)(&xs[idx * 8]), 16, 0, 0);
    }
  }
  asm volatile("s_waitcnt vmcnt(0)" ::: "memory");
  __syncthreads();

  const int l16  = lane & 15;
  const int cig  = lane >> 4;      // 0..3
  const int co_base = wid * 64;
  const int rowd = cig * 4;

  // per-lane pixel tables: frag fr covers p = fr*16 + l16 (0..111)
  int rp[7], owp[7];
  #pragma unroll
  for (int fr = 0; fr < 7; ++fr) {
    int p = fr * 16 + l16;
    rp[fr]  = (p < 54) ? 0 : 1;          // pad px (>=108) use row 1: in-slab
    owp[fr] = p - rp[fr] * 54;           // 0..53 valid; 54..57 pad -> slab pad
  }

  floatx4 acc[4][7];
  #pragma unroll
  for (int m = 0; m < 4; ++m)
    #pragma unroll
    for (int fr = 0; fr < 7; ++fr)
      acc[m][fr] = (floatx4){0.f, 0.f, 0.f, 0.f};

  #pragma unroll
  for (int s = 0; s < 36; ++s) {
    const int kh = s / 12, ch = (s / 3) & 3, kw = s % 3;
    // A fragments: direct from global (L2-resident repacked weights)
    const unsigned short* wp =
        w2 + ((size_t)(((kh * 3 + kw) * 16 + (ch * 4 + cig)) * COUT + co_base + l16)) * 8;
    short8 a[4];
    #pragma unroll
    for (int m = 0; m < 4; ++m)
      a[m] = *reinterpret_cast<const short8*>(wp + m * 128);
    // B fragments: per-lane (row,iw) swizzled LDS reads
    const int chb = ch * 4 + cig;
    short8 b[7];
    #pragma unroll
    for (int fr = 0; fr < 7; ++fr) {
      const int iwl = owp[fr] + kw;
      const int c16x = chb ^ (iwl & 7);
      const int boff = ((rp[fr] + kh) * 896 + iwl * 16 + c16x) * 8;
      b[fr] = *reinterpret_cast<const short8*>(&xs[boff]);
    }

    __builtin_amdgcn_s_setprio(1);
    #pragma unroll
    for (int m = 0; m < 4; ++m)
      #pragma unroll
      for (int fr = 0; fr < 7; ++fr)
        acc[m][fr] = __builtin_amdgcn_mfma_f32_16x16x32_bf16(a[m], b[fr], acc[m][fr], 0, 0, 0);
    __builtin_amdgcn_s_setprio(0);
  }

  // ---- epilogue: C/D col=lane&15 (pixel), row=(lane>>4)*4+reg (co) ----
  #pragma unroll
  for (int m = 0; m < 4; ++m) {
    #pragma unroll
    for (int reg = 0; reg < 4; ++reg) {
      int co = co_base + m * 16 + rowd + reg;
      float bvv = bias[co];
      float* opb = out + (((size_t)n * COUT + co) * OH + oh0) * OW;
      #pragma unroll
      for (int fr = 0; fr < 7; ++fr) {
        int p = fr * 16 + l16;
        if (p < 108)
          opb[rp[fr] * OW + owp[fr]] = acc[m][fr][reg] + bvv;
      }
    }
  }
}

// ================== fallback path (ws too small): round-2 kernel ==================
#define CSTR 136
#define IWP 66

__global__ __launch_bounds__(512, 4) void conv_fb(
    const float* __restrict__ x, const unsigned short* __restrict__ w2,
    const float* __restrict__ bias, float* __restrict__ out) {
  __shared__ alignas(16) unsigned short xsf[4 * IWP * CSTR];

  const int ohp = blockIdx.x;
  const int n   = blockIdx.y;
  const int oh0 = ohp * 2;
  const int tid = threadIdx.x;

  {
    short8 zz = {0, 0, 0, 0, 0, 0, 0, 0};
    for (int i = tid; i < 4 * 10 * 17; i += 512) {
      int r = i / 170, rem = i % 170;
      int iw = 56 + rem / 17, g = rem % 17;
      *reinterpret_cast<short8*>(&xsf[(r * IWP + iw) * CSTR + g * 8]) = zz;
    }
  }
  for (int s = tid; s < 3584; s += 512) {
    int iw = s % 56;
    int t  = s / 56;
    int c8 = t & 15, r = t >> 4;
    const float* xp = x + (size_t)n * CIN * (H * W) + (oh0 + r) * W + iw;
    short8 v;
    #pragma unroll
    for (int j = 0; j < 8; ++j)
      v[j] = (short)f2bf(xp[(size_t)(c8 * 8 + j) * (H * W)]);
    *reinterpret_cast<short8*>(&xsf[(r * IWP + iw) * CSTR + c8 * 8]) = v;
  }
  __syncthreads();

  const int wid  = tid >> 6;
  const int lane = tid & 63;
  const int wm   = wid >> 1;
  const int wn   = wid & 1;
  const int l16  = lane & 15;
  const int cig  = lane >> 4;

  const int co_base = wm * 64;
  const int oh = oh0 + wn;

  floatx4 acc[4][4];
  #pragma unroll
  for (int m = 0; m < 4; ++m)
    #pragma unroll
    for (int nr = 0; nr < 4; ++nr)
      acc[m][nr] = (floatx4){0.f, 0.f, 0.f, 0.f};

  for (int kh = 0; kh < 3; ++kh) {
    const int row = wn + kh;
    #pragma unroll
    for (int ch = 0; ch < 4; ++ch) {
      const int bbase = (row * IWP + l16) * CSTR + ch * 32 + cig * 8;
      #pragma unroll
      for (int kw = 0; kw < 3; ++kw) {
        const unsigned short* wp =
            w2 + ((size_t)(((kh * 3 + kw) * 16 + (ch * 4 + cig)) * COUT + co_base + l16)) * 8;
        short8 a[4];
        #pragma unroll
        for (int m = 0; m < 4; ++m)
          a[m] = *reinterpret_cast<const short8*>(wp + m * 16 * 8);
        short8 b[4];
        #pragma unroll
        for (int nr = 0; nr < 4; ++nr)
          b[nr] = *reinterpret_cast<const short8*>(&xsf[bbase + (nr * 16 + kw) * CSTR]);
        #pragma unroll
        for (int m = 0; m < 4; ++m)
          #pragma unroll
          for (int nr = 0; nr < 4; ++nr)
            acc[m][nr] = __builtin_amdgcn_mfma_f32_16x16x32_bf16(a[m], b[nr], acc[m][nr], 0, 0, 0);
      }
    }
  }

  const int rowd = cig * 4;
  #pragma unroll
  for (int m = 0; m < 4; ++m) {
    #pragma unroll
    for (int reg = 0; reg < 4; ++reg) {
      int co = co_base + m * 16 + rowd + reg;
      float bvv = bias[co];
      float* op = out + (((size_t)n * COUT + co) * OH + oh) * OW;
      #pragma unroll
      for (int nr = 0; nr < 4; ++nr) {
        int ow = nr * 16 + l16;
        if (ow < OW) op[ow] = acc[m][nr][reg] + bvv;
      }
    }
  }
}

extern "C" void kernel_launch(void* const* d_in, const int* in_sizes, int n_in,
                              void* d_out, int out_size, void* d_ws, size_t ws_size,
                              hipStream_t stream) {
  (void)in_sizes; (void)n_in; (void)out_size;
  const float* x    = (const float*)d_in[0];
  const float* w    = (const float*)d_in[1];
  const float* bias = (const float*)d_in[2];
  float* out = (float*)d_out;

  const size_t W2_BYTES = (size_t)9 * 16 * COUT * 8 * 2;            // 589,824
  const size_t XB_BYTES = (size_t)32 * H * 896 * 8 * 2;             // 25,690,112
  unsigned short* w2 = (unsigned short*)d_ws;

  repack_w<<<dim3((COUT * CIN * 9 + 255) / 256), dim3(256), 0, stream>>>(w, w2);

  if (ws_size >= W2_BYTES + XB_BYTES) {
    unsigned short* xb = (unsigned short*)((char*)d_ws + W2_BYTES);
    repack_x<<<dim3(56, 32), dim3(256), 0, stream>>>(x, xb);
    conv8<<<dim3(864), dim3(256), 0, stream>>>(xb, w2, bias, out);
  } else {
    conv_fb<<<dim3(27, 32), dim3(512), 0, stream>>>(x, w2, bias, out);
  }
}

// Round 16
// 84.661 us; speedup vs baseline: 1.1283x; 1.0037x over previous
//
#include <hip/hip_runtime.h>
#include <hip/hip_bf16.h>

#define CIN 128
#define COUT 256
#define H 56
#define W 56
#define OH 54
#define OW 54

typedef __attribute__((ext_vector_type(8))) short short8;
typedef __attribute__((ext_vector_type(4))) float floatx4;

typedef __attribute__((address_space(3))) unsigned int  lds_u32;
typedef const __attribute__((address_space(1))) unsigned int glb_u32;

static __device__ __forceinline__ unsigned short f2bf(float f) {
  unsigned int u = __builtin_bit_cast(unsigned int, f);
  u += 0x7fffu + ((u >> 16) & 1u);   // RNE
  return (unsigned short)(u >> 16);
}

// ---------- prepass 1: w[co][ci][kh][kw] f32 -> w2[k16][co][8] bf16 ----------
__global__ void repack_w(const float* __restrict__ w, unsigned short* __restrict__ w2) {
  int idx = blockIdx.x * 256 + threadIdx.x;
  if (idx >= COUT * CIN * 9) return;
  int kw = idx % 3, t1 = idx / 3;
  int kh = t1 % 3, t2 = t1 / 3;
  int ci = t2 % CIN;
  int co = t2 / CIN;
  int c8 = ci >> 3, j = ci & 7;
  w2[((((kh * 3 + kw) * 16 + c8) * COUT + co) * 8) + j] = f2bf(w[idx]);
}

// ---------- prepass 2 (LDS transpose, coalesced both sides) ----------
// x NCHW f32 -> xb[n][h][g'] bf16, g' = iw*16 + (c16 ^ (iw&7)).
__global__ __launch_bounds__(256) void repack_x(const float* __restrict__ x,
                                                unsigned short* __restrict__ xb) {
  __shared__ float xt[56][129];
  const int h = blockIdx.x;       // 0..55
  const int n = blockIdx.y;       // 0..31
  const float* src = x + (size_t)n * CIN * (H * W) + h * W;
  #pragma unroll
  for (int r = 0; r < 28; ++r) {
    int idx = r * 256 + threadIdx.x;
    int ci = idx / 56, iw = idx % 56;
    xt[iw][ci] = src[ci * (H * W) + iw];
  }
  __syncthreads();
  unsigned short* dst = xb + ((size_t)n * H + h) * 896 * 8;
  #pragma unroll
  for (int r = 0; r < 4; ++r) {
    int g = r * 256 + threadIdx.x;
    if (g < 896) {
      int iw = g >> 4, c16 = g & 15;
      short8 v;
      #pragma unroll
      for (int j = 0; j < 8; ++j)
        v[j] = (short)f2bf(xt[iw][c16 * 8 + j]);
      int gp = iw * 16 + (c16 ^ (iw & 7));
      *reinterpret_cast<short8*>(&dst[gp * 8]) = v;
    }
  }
}

// ---------- main conv: conv8 + OPAQUE (inline-asm) depth-2 A pipeline ----------
// Volatile asm global_load_dwordx4 cannot be rematerialized/sunk by the
// scheduler (the defeat mode of r4/r7/r8/r10). Counted s_waitcnt vmcnt(8)
// keeps 8 loads in flight; sched_barrier(0) stops MFMA hoisting (rule #18).
__global__ __launch_bounds__(256, 2) void conv9(
    const unsigned short* __restrict__ xb, const unsigned short* __restrict__ w2,
    const float* __restrict__ bias, float* __restrict__ out) {
  __shared__ alignas(16) unsigned short xs[3744 * 8];   // 4 rows + overrun pad = 59,904 B

  // XCD-bijective swizzle: 864 % 8 == 0
  const int f = blockIdx.x;
  const int swz = (f & 7) * 108 + (f >> 3);
  const int ohp = swz % 27;
  const int n   = swz / 27;
  const int oh0 = ohp * 2;
  const int tid = threadIdx.x;
  const int wid  = tid >> 6;       // co group (0..3)
  const int lane = tid & 63;

  // ---- stage rows oh0..oh0+3 (3584 granules), 14 issues/wave ----
  {
    const unsigned short* src = xb + ((size_t)n * H + oh0) * 896 * 8;
    #pragma unroll
    for (int i = 0; i < 14; ++i) {
      int idx = (wid * 14 + i) * 64;
      __builtin_amdgcn_global_load_lds(
          (glb_u32*)(src + (size_t)(idx + lane) * 8),
          (lds_u32*)(&xs[idx * 8]), 16, 0, 0);
    }
  }
  asm volatile("s_waitcnt vmcnt(0)" ::: "memory");
  __syncthreads();

  const int l16  = lane & 15;
  const int cig  = lane >> 4;      // 0..3
  const int co_base = wid * 64;
  const int rowd = cig * 4;

  // per-lane pixel tables: frag fr covers p = fr*16 + l16 (0..111)
  int rp[7], owp[7];
  #pragma unroll
  for (int fr = 0; fr < 7; ++fr) {
    int p = fr * 16 + l16;
    rp[fr]  = (p < 54) ? 0 : 1;
    owp[fr] = p - rp[fr] * 54;
  }

  floatx4 acc[4][7];
  #pragma unroll
  for (int m = 0; m < 4; ++m)
    #pragma unroll
    for (int fr = 0; fr < 7; ++fr)
      acc[m][fr] = (floatx4){0.f, 0.f, 0.f, 0.f};

  short8 areg[3][4];   // 3-slot rotation, 48 VGPRs; slots (s, s+1, s+2) disjoint mod 3

  // issue 4 A-loads for step s into slot: OPAQUE to the scheduler
#define AISSUE(s, slot)                                                          \
  {                                                                              \
    const int kh_ = (s) / 12, ch_ = ((s) / 3) & 3, kw_ = (s) % 3;                \
    const unsigned short* wp_ =                                                  \
        w2 + ((size_t)(((kh_ * 3 + kw_) * 16 + (ch_ * 4 + cig)) * COUT + co_base + l16)) * 8; \
    asm volatile("global_load_dwordx4 %0, %1, off"            : "=v"(areg[slot][0]) : "v"(wp_)); \
    asm volatile("global_load_dwordx4 %0, %1, off offset:256" : "=v"(areg[slot][1]) : "v"(wp_)); \
    asm volatile("global_load_dwordx4 %0, %1, off offset:512" : "=v"(areg[slot][2]) : "v"(wp_)); \
    asm volatile("global_load_dwordx4 %0, %1, off offset:768" : "=v"(areg[slot][3]) : "v"(wp_)); \
  }

  AISSUE(0, 0);
  AISSUE(1, 1);

  #pragma unroll
  for (int s = 0; s < 36; ++s) {
    if (s + 2 < 36) AISSUE(s + 2, (s + 2) % 3);

    // B fragments (LDS; lgkmcnt handled by compiler) — issue before the vm wait
    const int kh = s / 12, ch = (s / 3) & 3, kw = s % 3;
    const int chb = ch * 4 + cig;
    short8 b[7];
    #pragma unroll
    for (int fr = 0; fr < 7; ++fr) {
      const int iwl = owp[fr] + kw;
      const int c16x = chb ^ (iwl & 7);
      const int boff = ((rp[fr] + kh) * 896 + iwl * 16 + c16x) * 8;
      b[fr] = *reinterpret_cast<const short8*>(&xs[boff]);
    }

    // counted wait: A(s) landed; A(s+1), A(s+2) stay in flight
    if (s < 34)       asm volatile("s_waitcnt vmcnt(8)" ::: "memory");
    else if (s == 34) asm volatile("s_waitcnt vmcnt(4)" ::: "memory");
    else              asm volatile("s_waitcnt vmcnt(0)" ::: "memory");
    __builtin_amdgcn_sched_barrier(0);   // MFMA may not hoist above the wait

    __builtin_amdgcn_s_setprio(1);
    #pragma unroll
    for (int m = 0; m < 4; ++m)
      #pragma unroll
      for (int fr = 0; fr < 7; ++fr)
        acc[m][fr] = __builtin_amdgcn_mfma_f32_16x16x32_bf16(
            areg[s % 3][m], b[fr], acc[m][fr], 0, 0, 0);
    __builtin_amdgcn_s_setprio(0);
  }
#undef AISSUE

  // ---- epilogue: C/D col=lane&15 (pixel), row=(lane>>4)*4+reg (co) ----
  #pragma unroll
  for (int m = 0; m < 4; ++m) {
    #pragma unroll
    for (int reg = 0; reg < 4; ++reg) {
      int co = co_base + m * 16 + rowd + reg;
      float bvv = bias[co];
      float* opb = out + (((size_t)n * COUT + co) * OH + oh0) * OW;
      #pragma unroll
      for (int fr = 0; fr < 7; ++fr) {
        int p = fr * 16 + l16;
        if (p < 108)
          opb[rp[fr] * OW + owp[fr]] = acc[m][fr][reg] + bvv;
      }
    }
  }
}

// ================== fallback path (ws too small): round-2 kernel ==================
#define CSTR 136
#define IWP 66

__global__ __launch_bounds__(512, 4) void conv_fb(
    const float* __restrict__ x, const unsigned short* __restrict__ w2,
    const float* __restrict__ bias, float* __restrict__ out) {
  __shared__ alignas(16) unsigned short xsf[4 * IWP * CSTR];

  const int ohp = blockIdx.x;
  const int n   = blockIdx.y;
  const int oh0 = ohp * 2;
  const int tid = threadIdx.x;

  {
    short8 zz = {0, 0, 0, 0, 0, 0, 0, 0};
    for (int i = tid; i < 4 * 10 * 17; i += 512) {
      int r = i / 170, rem = i % 170;
      int iw = 56 + rem / 17, g = rem % 17;
      *reinterpret_cast<short8*>(&xsf[(r * IWP + iw) * CSTR + g * 8]) = zz;
    }
  }
  for (int s = tid; s < 3584; s += 512) {
    int iw = s % 56;
    int t  = s / 56;
    int c8 = t & 15, r = t >> 4;
    const float* xp = x + (size_t)n * CIN * (H * W) + (oh0 + r) * W + iw;
    short8 v;
    #pragma unroll
    for (int j = 0; j < 8; ++j)
      v[j] = (short)f2bf(xp[(size_t)(c8 * 8 + j) * (H * W)]);
    *reinterpret_cast<short8*>(&xsf[(r * IWP + iw) * CSTR + c8 * 8]) = v;
  }
  __syncthreads();

  const int wid  = tid >> 6;
  const int lane = tid & 63;
  const int wm   = wid >> 1;
  const int wn   = wid & 1;
  const int l16  = lane & 15;
  const int cig  = lane >> 4;

  const int co_base = wm * 64;
  const int oh = oh0 + wn;

  floatx4 acc[4][4];
  #pragma unroll
  for (int m = 0; m < 4; ++m)
    #pragma unroll
    for (int nr = 0; nr < 4; ++nr)
      acc[m][nr] = (floatx4){0.f, 0.f, 0.f, 0.f};

  for (int kh = 0; kh < 3; ++kh) {
    const int row = wn + kh;
    #pragma unroll
    for (int ch = 0; ch < 4; ++ch) {
      const int bbase = (row * IWP + l16) * CSTR + ch * 32 + cig * 8;
      #pragma unroll
      for (int kw = 0; kw < 3; ++kw) {
        const unsigned short* wp =
            w2 + ((size_t)(((kh * 3 + kw) * 16 + (ch * 4 + cig)) * COUT + co_base + l16)) * 8;
        short8 a[4];
        #pragma unroll
        for (int m = 0; m < 4; ++m)
          a[m] = *reinterpret_cast<const short8*>(wp + m * 16 * 8);
        short8 b[4];
        #pragma unroll
        for (int nr = 0; nr < 4; ++nr)
          b[nr] = *reinterpret_cast<const short8*>(&xsf[bbase + (nr * 16 + kw) * CSTR]);
        #pragma unroll
        for (int m = 0; m < 4; ++m)
          #pragma unroll
          for (int nr = 0; nr < 4; ++nr)
            acc[m][nr] = __builtin_amdgcn_mfma_f32_16x16x32_bf16(a[m], b[nr], acc[m][nr], 0, 0, 0);
      }
    }
  }

  const int rowd = cig * 4;
  #pragma unroll
  for (int m = 0; m < 4; ++m) {
    #pragma unroll
    for (int reg = 0; reg < 4; ++reg) {
      int co = co_base + m * 16 + rowd + reg;
      float bvv = bias[co];
      float* op = out + (((size_t)n * COUT + co) * OH + oh) * OW;
      #pragma unroll
      for (int nr = 0; nr < 4; ++nr) {
        int ow = nr * 16 + l16;
        if (ow < OW) op[ow] = acc[m][nr][reg] + bvv;
      }
    }
  }
}

extern "C" void kernel_launch(void* const* d_in, const int* in_sizes, int n_in,
                              void* d_out, int out_size, void* d_ws, size_t ws_size,
                              hipStream_t stream) {
  (void)in_sizes; (void)n_in; (void)out_size;
  const float* x    = (const float*)d_in[0];
  const float* w    = (const float*)d_in[1];
  const float* bias = (const float*)d_in[2];
  float* out = (float*)d_out;

  const size_t W2_BYTES = (size_t)9 * 16 * COUT * 8 * 2;            // 589,824
  const size_t XB_BYTES = (size_t)32 * H * 896 * 8 * 2;             // 25,690,112
  unsigned short* w2 = (unsigned short*)d_ws;

  repack_w<<<dim3((COUT * CIN * 9 + 255) / 256), dim3(256), 0, stream>>>(w, w2);

  if (ws_size >= W2_BYTES + XB_BYTES) {
    unsigned short* xb = (unsigned short*)((char*)d_ws + W2_BYTES);
    repack_x<<<dim3(56, 32), dim3(256), 0, stream>>>(x, xb);
    conv9<<<dim3(864), dim3(256), 0, stream>>>(xb, w2, bias, out);
  } else {
    conv_fb<<<dim3(27, 32), dim3(512), 0, stream>>>(x, w2, bias, out);
  }
}